// Round 12
// baseline (249.918 us; speedup 1.0000x reference)
//
#include <hip/hip_runtime.h>

typedef _Float16 f16;
typedef f16  f16x4 __attribute__((ext_vector_type(4)));
typedef f16  f16x8 __attribute__((ext_vector_type(8)));
typedef __fp16 h16x2 __attribute__((ext_vector_type(2)));  // cvt_pkrtz native return type
typedef float f32x4  __attribute__((ext_vector_type(4)));
typedef float f32x16 __attribute__((ext_vector_type(16)));
typedef unsigned int u32;
typedef u32 u32x2 __attribute__((ext_vector_type(2)));
typedef u32 u32x4 __attribute__((ext_vector_type(4)));

#define LOG2E   1.4426950408889634f
#define LN2     0.6931471805599453f
#define C_TANH  2.8853900817779268f    // 2*log2(e)
#define C_SIN   0.15915494309189535f   // 1/(2*pi)
#define C_SIG  -1.4426950408889634f    // -log2(e)
#define C_GAU  -0.7213475204444817f    // -log2(e)/2

// per-node arg prescale baked into W,b at prep: acts 0=tanh,1=elu,2=softplus,3=sin,4=gauss,5=sigmoid
__device__ __constant__ float NSCL[12] = {
    C_TANH, C_TANH, 1.0f, 1.0f, C_SIN, 1.0f, C_SIG, C_TANH, 1.0f, 1.0f, C_SIN, 1.0f
};

__device__ __forceinline__ float frcp(float x){ return __builtin_amdgcn_rcpf(x); }
__device__ __forceinline__ float fexp2(float x){ return __builtin_amdgcn_exp2f(x); }
__device__ __forceinline__ float flog2(float x){ return __builtin_amdgcn_logf(x); }
__device__ __forceinline__ float fsin1(float x){ return __builtin_amdgcn_sinf(x); } // arg in revolutions

// ---------- activations on PRESCALED args (see NSCL) ----------
template<int A> __device__ __forceinline__ float act(float v){
    if constexpr (A == 0){                       // tanh; v = 2log2e*x
        float t = fexp2(v);
        return 1.0f - 2.0f * frcp(1.0f + t);
    } else if constexpr (A == 1){                // elu; v raw
        float e = fexp2(v * LOG2E) - 1.0f;
        return v > 0.0f ? v : e;
    } else if constexpr (A == 2){                // softplus; v raw
        float p = fexp2(-LOG2E * fabsf(v));
        return fmaxf(v, 0.0f) + LN2 * flog2(1.0f + p);
    } else if constexpr (A == 3){                // sin; v = x/(2pi)
        return fsin1(v);
    } else if constexpr (A == 4){                // gauss; v raw
        return fexp2(v * v * C_GAU);
    } else {                                     // sigmoid; v = -log2e*x
        return frcp(1.0f + fexp2(v));
    }
}

__device__ __forceinline__ f16x4 pack4(float a, float b, float c, float d){
    u32x2 u;
    u[0] = __builtin_bit_cast(u32, __builtin_amdgcn_cvt_pkrtz(a, b));
    u[1] = __builtin_bit_cast(u32, __builtin_amdgcn_cvt_pkrtz(c, d));
    return __builtin_bit_cast(f16x4, u);
}
__device__ __forceinline__ f16x8 cat8(f16x4 lo, f16x4 hi){
    u32x2 a = __builtin_bit_cast(u32x2, lo), b = __builtin_bit_cast(u32x2, hi);
    u32x4 u; u[0] = a[0]; u[1] = a[1]; u[2] = b[0]; u[3] = b[1];
    return __builtin_bit_cast(f16x8, u);
}

#define MFMA32(a, b, c) __builtin_amdgcn_mfma_f32_32x32x16_f16((a), (b), (c), 0, 0, 0)

// K-permutation pi: k-slot (kc, 8h+j) holds feature 8*kc + 32*(j>>2) + 4*h + (j&3);
// next node's B-frag[kc] = cat(pk[t=0][g=kc], pk[t=1][g=kc]) -- registers only.
//
// Dual-tile node: ONE A-frag / bias read feeds BOTH tiles (P,Q). NP = #predecessors;
// predecessor sums are formed at point of use (transient) to cap register pressure.
template<int ACTI, int NP>
__device__ __forceinline__ void node32x2(const f16* __restrict__ wr,   // &wfrag[ni][0][0][lane][0]
                                         const float* __restrict__ bs, // &b_s[ni][0] (prescaled)
                                         const int hf4,                // 4*(lane>>5)
                                         const f16x8 A0[2][4], const f16x8 A1[2][4], const f16x8 A2[2][4],
                                         f16x8 OUT[2][4])
{
    f16x4 pkP[2][4], pkQ[2][4];
    #pragma unroll
    for (int t = 0; t < 2; ++t){
        f32x16 aP, aQ;
        #pragma unroll
        for (int g = 0; g < 4; ++g){
            f32x4 bv = *(const f32x4*)(bs + 32 * t + 8 * g + hf4);
            aP[4*g+0] = bv[0]; aP[4*g+1] = bv[1]; aP[4*g+2] = bv[2]; aP[4*g+3] = bv[3];
            aQ[4*g+0] = bv[0]; aQ[4*g+1] = bv[1]; aQ[4*g+2] = bv[2]; aQ[4*g+3] = bv[3];
        }
        #pragma unroll
        for (int kc = 0; kc < 4; ++kc){
            f16x8 Af = *(const f16x8*)(wr + t * 2048 + kc * 512);
            f16x8 bP = A0[0][kc], bQ = A0[1][kc];
            if constexpr (NP >= 2){ bP = bP + A1[0][kc]; bQ = bQ + A1[1][kc]; }
            if constexpr (NP >= 3){ bP = bP + A2[0][kc]; bQ = bQ + A2[1][kc]; }
            aP = MFMA32(Af, bP, aP);
            aQ = MFMA32(Af, bQ, aQ);
        }
        #pragma unroll
        for (int g = 0; g < 4; ++g){
            pkP[t][g] = pack4(act<ACTI>(aP[4*g+0]), act<ACTI>(aP[4*g+1]),
                              act<ACTI>(aP[4*g+2]), act<ACTI>(aP[4*g+3]));
            pkQ[t][g] = pack4(act<ACTI>(aQ[4*g+0]), act<ACTI>(aQ[4*g+1]),
                              act<ACTI>(aQ[4*g+2]), act<ACTI>(aQ[4*g+3]));
        }
    }
    #pragma unroll
    for (int kc = 0; kc < 4; ++kc){
        OUT[0][kc] = cat8(pkP[0][kc], pkP[1][kc]);
        OUT[1][kc] = cat8(pkQ[0][kc], pkQ[1][kc]);
    }
}

__global__ __launch_bounds__(1024, 1) void inr_mfma10_kernel(
    const float* __restrict__ gx, const float* __restrict__ gy,
    const float* __restrict__ gz, const float* __restrict__ gr,
    const float* __restrict__ gnoise,
    const float* __restrict__ W_noise, const float* __restrict__ b_noise,
    const float* __restrict__ W_x, const float* __restrict__ W_y,
    const float* __restrict__ W_z, const float* __restrict__ W_r,
    const float* __restrict__ W1, const float* __restrict__ b1,
    const float* __restrict__ Wg, const float* __restrict__ bg,
    const float* __restrict__ W_out, const float* __restrict__ b_out,
    float* __restrict__ out, int ngrp, int niter)
{
    // ---- LDS ~106 KB, 1 block (16 waves) per CU -> 4 waves/SIMD x dual-stream ----
    __shared__ __align__(16) f16   wfrag[12][2][4][64][8]; // 96 KB  prescaled W^T A-frags, pi-permuted k
    __shared__ __align__(16) f16   nfrag[2][64][8];        //  2 KB  2log2e*W_noise^T
    __shared__ __align__(16) f16   ofrag[4][64][8];        //  4 KB  -log2e*W_out^T (pi, rows>=3 zero)
    __shared__ __align__(16) float b_s[12][64];            //  3 KB  prescaled biases
    __shared__ __align__(16) float wvs[4][64];             //  1 KB  [0]=C_GAU*Wx^2, [1]=2log2e*Wy, [2]=Wz, [3]=Wr
    __shared__ __align__(16) float bns[64];                //  256B  2log2e*b_noise
    __shared__            float bout_s[4];

    const int tid  = threadIdx.x;
    const int lane = tid & 63;
    const int n2   = lane & 31;      // point-in-tile (MFMA col)
    const int hf   = lane >> 5;      // half-wave
    const int hf4  = 4 * hf;

    // ================= PREP: barrier-free direct global->frag (grid=256 -> once per CU) ======
    if (tid < 768){
        int node = tid >> 6, f = tid & 63;
        b_s[node][f] = NSCL[node] * ((node == 0) ? b1[f] : bg[(node - 1) * 64 + f]);
    }
    if (tid < 256){
        int vec = tid >> 6, f = tid & 63;
        float v;
        if      (vec == 0){ float w = W_x[f]; v = C_GAU * w * w; }
        else if (vec == 1){ v = C_TANH * W_y[f]; }
        else if (vec == 2){ v = W_z[f]; }
        else              { v = W_r[f]; }
        wvs[vec][f] = v;
    }
    if (tid < 64) bns[tid] = C_TANH * b_noise[tid];
    if (tid < 4)  bout_s[tid] = (tid < 3) ? C_SIG * b_out[tid] : 0.0f;
    if (tid < 128){                                  // nfrag: A[m][k]=2log2e*W_noise[k][m], k=8h+j
        int t = tid >> 6, ln = tid & 63, m = ln & 31, h = ln >> 5;
        f16x8 v;
        #pragma unroll
        for (int j = 0; j < 8; ++j) v[j] = (f16)(C_TANH * W_noise[(8 * h + j) * 64 + 32 * t + m]);
        *(f16x8*)&nfrag[t][ln][0] = v;
    }
    if (tid < 256){                                  // ofrag: A[m][k]=-log2e*W_out[pi][m] (m<3)
        int kc = tid >> 6, ln = tid & 63, m = ln & 31, h = ln >> 5;
        f16x8 v;
        #pragma unroll
        for (int j = 0; j < 8; ++j){
            int kf = 8 * kc + 32 * (j >> 2) + 4 * h + (j & 3);
            v[j] = (m < 3) ? (f16)(C_SIG * W_out[kf * 3 + m]) : (f16)0.0f;
        }
        *(f16x8*)&ofrag[kc][ln][0] = v;
    }
    // big weights: threads 0..511 each build one f16x8 A-frag per node straight from global
    // (L2-hot), one ds_write_b128 each, no intermediate barriers
    if (tid < 512){
        const int t = tid >> 8, kc = (tid >> 6) & 3, ln = tid & 63, m = ln & 31, h = ln >> 5;
        int kfo[8];
        #pragma unroll
        for (int j = 0; j < 8; ++j)
            kfo[j] = (8 * kc + 32 * (j >> 2) + 4 * h + (j & 3)) * 64 + 32 * t + m;
        #pragma unroll
        for (int node = 0; node < 12; ++node){
            const float* Wsrc = (node == 0) ? W1 : (Wg + (node - 1) * 4096);
            const float  scl  = NSCL[node];
            f16x8 v;
            #pragma unroll
            for (int j = 0; j < 8; ++j) v[j] = (f16)(scl * Wsrc[kfo[j]]);
            *(f16x8*)&wfrag[node][t][kc][ln][0] = v;
        }
    }
    __syncthreads();   // single barrier: all fragments complete

    #define WPTR(NI) (&wfrag[NI][0][0][lane][0])
    #define N1(NI, ACTI, A, OUT)        node32x2<ACTI,1>(WPTR(NI), &b_s[NI][0], hf4, A, A, A, OUT)
    #define N2(NI, ACTI, A, B, OUT)     node32x2<ACTI,2>(WPTR(NI), &b_s[NI][0], hf4, A, B, B, OUT)
    #define N3(NI, ACTI, A, B, C, OUT)  node32x2<ACTI,3>(WPTR(NI), &b_s[NI][0], hf4, A, B, C, OUT)

    const int wvid = tid >> 6;       // wave id 0..15

    // ================= MAIN LOOP: one dual-group (64 pts) per wave per iter =================
    for (int it = 0; it < niter; ++it){
        const int grp = (it * gridDim.x + blockIdx.x) * 16 + wvid;
        if (grp >= ngrp) break;
        const int tbase = grp * 2;

        f16x8 sg[2][4];
        int myp2[2];
        #pragma unroll
        for (int tt = 0; tt < 2; ++tt){
            const int myp = (tbase + tt) * 32 + n2;
            myp2[tt] = myp;
            const float xs = gx[myp], ys = gy[myp], zs = gz[myp], rs = gr[myp];
            const float xs2 = xs * xs;
            f16x8 nb;
            {
                const float4 a4 = *(const float4*)(gnoise + (size_t)myp * 16 + 8 * hf);
                const float4 b4 = *(const float4*)(gnoise + (size_t)myp * 16 + 8 * hf + 4);
                nb = cat8(pack4(a4.x, a4.y, a4.z, a4.w), pack4(b4.x, b4.y, b4.z, b4.w));
            }
            f16x4 pkg[2][4];
            #pragma unroll
            for (int t = 0; t < 2; ++t){
                f32x16 ac;
                #pragma unroll
                for (int i = 0; i < 16; ++i) ac[i] = 0.0f;
                ac = MFMA32(*(const f16x8*)&nfrag[t][lane][0], nb, ac);
                #pragma unroll
                for (int g = 0; g < 4; ++g){
                    const int fb = 32 * t + 8 * g + hf4;
                    const f32x4 wx2 = *(const f32x4*)&wvs[0][fb];   // C_GAU*Wx^2
                    const f32x4 wyt = *(const f32x4*)&wvs[1][fb];   // 2log2e*Wy
                    const f32x4 wz  = *(const f32x4*)&wvs[2][fb];
                    const f32x4 wr_ = *(const f32x4*)&wvs[3][fb];
                    const f32x4 bn  = *(const f32x4*)&bns[fb];      // 2log2e*b_noise
                    float gv[4];
                    #pragma unroll
                    for (int r = 0; r < 4; ++r){
                        float az = zs * wz[r];
                        float velu = az > 0.0f ? az : (fexp2(az * LOG2E) - 1.0f);
                        float vga = fexp2(xs2 * wx2[r]);
                        float vty = 1.0f - 2.0f * frcp(1.0f + fexp2(ys * wyt[r]));
                        float ar = rs * wr_[r];
                        float vsp = fmaxf(ar, 0.0f) + LN2 * flog2(1.0f + fexp2(-LOG2E * fabsf(ar)));
                        float vtp = 1.0f - 2.0f * frcp(1.0f + fexp2(ac[4 * g + r] + bn[r]));
                        gv[r] = fsin1((velu + vga + vty + vsp + vtp) * C_SIN);
                    }
                    pkg[t][g] = pack4(gv[0], gv[1], gv[2], gv[3]);
                }
            }
            #pragma unroll
            for (int kc = 0; kc < 4; ++kc) sg[tt][kc] = cat8(pkg[0][kc], pkg[1][kc]);
        }

        f16x8 h0[2][4], r0[2][4], r1[2][4], r2[2][4], r3[2][4];
        N1(0,  0, sg, h0);                 // h0 = tanh(g @ W1 + b1)
        N1(1,  0, h0, r0);                 // h1 = tanh(h0 W)
        N1(2,  1, r0, r1);                 // h2 = elu(h1 W)
        N2(3,  2, r1, h0, r2);             // h3 = softplus((h2+h0) W)
        N3(4,  3, r2, r0, h0, r3);         // h4 = sin((h3+h1+h0) W)
        N2(5,  4, r3, r1, r0);             // h5 = gauss((h4+h2) W)
        N2(6,  5, r0, r2, r1);             // h6 = sigmoid((h5+h3) W)
        N2(7,  0, r1, r3, r2);             // h7 = tanh((h6+h4) W)
        N3(8,  1, r2, r0, h0, r3);         // h8 = elu((h7+h5+h0) W)
        N2(9,  2, r3, r1, r0);             // h9 = softplus((h8+h6) W)
        N2(10, 3, r0, r2, r1);             // h10= sin((h9+h7) W)
        N2(11, 4, r1, r3, r2);             // h11= gauss((h10+h8) W)

        // ---- output: sigmoid folded into ofrag: out = rcp(1+exp2(om+bout)) ----
        #pragma unroll
        for (int tt = 0; tt < 2; ++tt){
            f32x16 om;
            #pragma unroll
            for (int i = 0; i < 16; ++i) om[i] = 0.0f;
            #pragma unroll
            for (int kc = 0; kc < 4; ++kc)
                om = MFMA32(*(const f16x8*)&ofrag[kc][lane][0], r2[tt][kc], om);
            if (hf == 0){
                #pragma unroll
                for (int r = 0; r < 3; ++r)
                    out[(size_t)myp2[tt] * 3 + r] = frcp(1.0f + fexp2(om[r] + bout_s[r]));
            }
        }
    }
    #undef N1
    #undef N2
    #undef N3
    #undef WPTR
}

extern "C" void kernel_launch(void* const* d_in, const int* in_sizes, int n_in,
                              void* d_out, int out_size, void* d_ws, size_t ws_size,
                              hipStream_t stream)
{
    const float* x       = (const float*)d_in[0];
    const float* y       = (const float*)d_in[1];
    const float* z       = (const float*)d_in[2];
    const float* r       = (const float*)d_in[3];
    const float* noise   = (const float*)d_in[4];
    const float* W_noise = (const float*)d_in[5];
    const float* b_noise = (const float*)d_in[6];
    const float* W_x     = (const float*)d_in[7];
    const float* W_y     = (const float*)d_in[8];
    const float* W_z     = (const float*)d_in[9];
    const float* W_r     = (const float*)d_in[10];
    const float* W1      = (const float*)d_in[11];
    const float* b1      = (const float*)d_in[12];
    const float* Wg      = (const float*)d_in[13];
    const float* bg      = (const float*)d_in[14];
    const float* W_out   = (const float*)d_in[15];
    const float* b_out   = (const float*)d_in[16];
    float* out = (float*)d_out;

    const int n     = in_sizes[0];
    const int ngrp  = n / 64;                       // dual-tile groups of 64 points (4096)
    const int grid  = 256;                          // 1 block per CU; prep once per CU
    const int grp_per_pass = grid * 16;             // 16 waves x 1 group = 4096 -> single pass
    const int niter = (ngrp + grp_per_pass - 1) / grp_per_pass;
    inr_mfma10_kernel<<<dim3(grid), dim3(1024), 0, stream>>>(
        x, y, z, r, noise, W_noise, b_noise, W_x, W_y, W_z, W_r,
        W1, b1, Wg, bg, W_out, b_out, out, ngrp, niter);
}

// Round 13
// 161.959 us; speedup vs baseline: 1.5431x; 1.5431x over previous
//
#include <hip/hip_runtime.h>

typedef _Float16 f16;
typedef f16  f16x4 __attribute__((ext_vector_type(4)));
typedef f16  f16x8 __attribute__((ext_vector_type(8)));
typedef __fp16 h16x2 __attribute__((ext_vector_type(2)));  // cvt_pkrtz native return type
typedef float f32x4  __attribute__((ext_vector_type(4)));
typedef float f32x16 __attribute__((ext_vector_type(16)));
typedef unsigned int u32;
typedef u32 u32x2 __attribute__((ext_vector_type(2)));
typedef u32 u32x4 __attribute__((ext_vector_type(4)));

#define LOG2E   1.4426950408889634f
#define LN2     0.6931471805599453f
#define C_TANH  2.8853900817779268f    // 2*log2(e)
#define C_SIN   0.15915494309189535f   // 1/(2*pi)
#define C_SIG  -1.4426950408889634f    // -log2(e)
#define C_GAU  -0.7213475204444817f    // -log2(e)/2

// per-node arg prescale baked into W,b at prep: acts 0=tanh,1=elu,2=softplus,3=sin,4=gauss,5=sigmoid
__device__ __constant__ float NSCL[12] = {
    C_TANH, C_TANH, 1.0f, 1.0f, C_SIN, 1.0f, C_SIG, C_TANH, 1.0f, 1.0f, C_SIN, 1.0f
};

__device__ __forceinline__ float frcp(float x){ return __builtin_amdgcn_rcpf(x); }
__device__ __forceinline__ float fexp2(float x){ return __builtin_amdgcn_exp2f(x); }
__device__ __forceinline__ float flog2(float x){ return __builtin_amdgcn_logf(x); }
__device__ __forceinline__ float fsin1(float x){ return __builtin_amdgcn_sinf(x); } // arg in revolutions

// ---------- activations on PRESCALED args (see NSCL) ----------
template<int A> __device__ __forceinline__ float act(float v){
    if constexpr (A == 0){                       // tanh; v = 2log2e*x
        float t = fexp2(v);
        return 1.0f - 2.0f * frcp(1.0f + t);
    } else if constexpr (A == 1){                // elu; v raw
        float e = fexp2(v * LOG2E) - 1.0f;
        return v > 0.0f ? v : e;
    } else if constexpr (A == 2){                // softplus; v raw
        float p = fexp2(-LOG2E * fabsf(v));
        return fmaxf(v, 0.0f) + LN2 * flog2(1.0f + p);
    } else if constexpr (A == 3){                // sin; v = x/(2pi)
        return fsin1(v);
    } else if constexpr (A == 4){                // gauss; v raw
        return fexp2(v * v * C_GAU);
    } else {                                     // sigmoid; v = -log2e*x
        return frcp(1.0f + fexp2(v));
    }
}

__device__ __forceinline__ f16x4 pack4(float a, float b, float c, float d){
    u32x2 u;
    u[0] = __builtin_bit_cast(u32, __builtin_amdgcn_cvt_pkrtz(a, b));
    u[1] = __builtin_bit_cast(u32, __builtin_amdgcn_cvt_pkrtz(c, d));
    return __builtin_bit_cast(f16x4, u);
}
__device__ __forceinline__ f16x8 cat8(f16x4 lo, f16x4 hi){
    u32x2 a = __builtin_bit_cast(u32x2, lo), b = __builtin_bit_cast(u32x2, hi);
    u32x4 u; u[0] = a[0]; u[1] = a[1]; u[2] = b[0]; u[3] = b[1];
    return __builtin_bit_cast(f16x8, u);
}

#define MFMA32(a, b, c) __builtin_amdgcn_mfma_f32_32x32x16_f16((a), (b), (c), 0, 0, 0)

// K-permutation pi: k-slot (kc, 8h+j) holds feature 8*kc + 32*(j>>2) + 4*h + (j&3);
// next node's B-frag[kc] = cat(pk[t=0][g=kc], pk[t=1][g=kc]) -- registers only.
//
// Dual-tile node: ONE A-frag / bias read feeds BOTH tiles (P,Q). NP = #predecessors;
// predecessor sums are formed at point of use (transient) to cap register pressure.
template<int ACTI, int NP>
__device__ __forceinline__ void node32x2(const f16* __restrict__ wr,   // &wfrag[ni][0][0][lane][0]
                                         const float* __restrict__ bs, // &b_s[ni][0] (prescaled)
                                         const int hf4,                // 4*(lane>>5)
                                         const f16x8 A0[2][4], const f16x8 A1[2][4], const f16x8 A2[2][4],
                                         f16x8 OUT[2][4])
{
    f16x4 pkP[2][4], pkQ[2][4];
    #pragma unroll
    for (int t = 0; t < 2; ++t){
        f32x16 aP, aQ;
        #pragma unroll
        for (int g = 0; g < 4; ++g){
            f32x4 bv = *(const f32x4*)(bs + 32 * t + 8 * g + hf4);
            aP[4*g+0] = bv[0]; aP[4*g+1] = bv[1]; aP[4*g+2] = bv[2]; aP[4*g+3] = bv[3];
            aQ[4*g+0] = bv[0]; aQ[4*g+1] = bv[1]; aQ[4*g+2] = bv[2]; aQ[4*g+3] = bv[3];
        }
        #pragma unroll
        for (int kc = 0; kc < 4; ++kc){
            f16x8 Af = *(const f16x8*)(wr + t * 2048 + kc * 512);
            f16x8 bP = A0[0][kc], bQ = A0[1][kc];
            if constexpr (NP >= 2){ bP = bP + A1[0][kc]; bQ = bQ + A1[1][kc]; }
            if constexpr (NP >= 3){ bP = bP + A2[0][kc]; bQ = bQ + A2[1][kc]; }
            aP = MFMA32(Af, bP, aP);
            aQ = MFMA32(Af, bQ, aQ);
        }
        #pragma unroll
        for (int g = 0; g < 4; ++g){
            pkP[t][g] = pack4(act<ACTI>(aP[4*g+0]), act<ACTI>(aP[4*g+1]),
                              act<ACTI>(aP[4*g+2]), act<ACTI>(aP[4*g+3]));
            pkQ[t][g] = pack4(act<ACTI>(aQ[4*g+0]), act<ACTI>(aQ[4*g+1]),
                              act<ACTI>(aQ[4*g+2]), act<ACTI>(aQ[4*g+3]));
        }
    }
    #pragma unroll
    for (int kc = 0; kc < 4; ++kc){
        OUT[0][kc] = cat8(pkP[0][kc], pkP[1][kc]);
        OUT[1][kc] = cat8(pkQ[0][kc], pkQ[1][kc]);
    }
}

__global__ __launch_bounds__(512, 2) void inr_mfma8_kernel(
    const float* __restrict__ gx, const float* __restrict__ gy,
    const float* __restrict__ gz, const float* __restrict__ gr,
    const float* __restrict__ gnoise,
    const float* __restrict__ W_noise, const float* __restrict__ b_noise,
    const float* __restrict__ W_x, const float* __restrict__ W_y,
    const float* __restrict__ W_z, const float* __restrict__ W_r,
    const float* __restrict__ W1, const float* __restrict__ b1,
    const float* __restrict__ Wg, const float* __restrict__ bg,
    const float* __restrict__ W_out, const float* __restrict__ b_out,
    float* __restrict__ out, int nt, int niter)
{
    // ---- LDS ~106 KB, 1 block (8 waves) per CU -> 2 waves/SIMD x dual-stream ----
    // NOTE (R11/R12 post-mortem): this (512,2) shape is the allocator sweet spot —
    // 128 arch VGPR + rings in unified AGPRs, zero spill. 768/(,3) and 1024/(,1)
    // both spill catastrophically (148/315 MB scratch writes). Do not raise.
    __shared__ __align__(16) f16   wfrag[12][2][4][64][8]; // 96 KB  prescaled W^T A-frags, pi-permuted k
    __shared__ __align__(16) f16   nfrag[2][64][8];        //  2 KB  2log2e*W_noise^T
    __shared__ __align__(16) f16   ofrag[4][64][8];        //  4 KB  -log2e*W_out^T (pi, rows>=3 zero)
    __shared__ __align__(16) float b_s[12][64];            //  3 KB  prescaled biases
    __shared__ __align__(16) float wvs[4][64];             //  1 KB  [0]=C_GAU*Wx^2, [1]=2log2e*Wy, [2]=Wz, [3]=Wr
    __shared__ __align__(16) float bns[64];                //  256B  2log2e*b_noise
    __shared__            float bout_s[4];

    const int tid  = threadIdx.x;
    const int lane = tid & 63;
    const int n2   = lane & 31;      // point-in-tile (MFMA col)
    const int hf   = lane >> 5;      // half-wave
    const int hf4  = 4 * hf;

    // ================= PREP: barrier-free direct global->frag (grid=256 -> once per CU) ======
    for (int i = tid; i < 768; i += 512){
        int node = i >> 6, f = i & 63;
        b_s[node][f] = NSCL[node] * ((node == 0) ? b1[f] : bg[(node - 1) * 64 + f]);
    }
    if (tid < 256){
        int vec = tid >> 6, f = tid & 63;
        float v;
        if      (vec == 0){ float w = W_x[f]; v = C_GAU * w * w; }
        else if (vec == 1){ v = C_TANH * W_y[f]; }
        else if (vec == 2){ v = W_z[f]; }
        else              { v = W_r[f]; }
        wvs[vec][f] = v;
    }
    if (tid < 64) bns[tid] = C_TANH * b_noise[tid];
    if (tid < 4)  bout_s[tid] = (tid < 3) ? C_SIG * b_out[tid] : 0.0f;
    if (tid < 128){                                  // nfrag: A[m][k]=2log2e*W_noise[k][m], k=8h+j
        int t = tid >> 6, ln = tid & 63, m = ln & 31, h = ln >> 5;
        f16x8 v;
        #pragma unroll
        for (int j = 0; j < 8; ++j) v[j] = (f16)(C_TANH * W_noise[(8 * h + j) * 64 + 32 * t + m]);
        *(f16x8*)&nfrag[t][ln][0] = v;
    }
    if (tid < 256){                                  // ofrag: A[m][k]=-log2e*W_out[pi][m] (m<3)
        int kc = tid >> 6, ln = tid & 63, m = ln & 31, h = ln >> 5;
        f16x8 v;
        #pragma unroll
        for (int j = 0; j < 8; ++j){
            int kf = 8 * kc + 32 * (j >> 2) + 4 * h + (j & 3);
            v[j] = (m < 3) ? (f16)(C_SIG * W_out[kf * 3 + m]) : (f16)0.0f;
        }
        *(f16x8*)&ofrag[kc][ln][0] = v;
    }
    // big weights: each thread builds one f16x8 A-frag per node straight from global (L2-hot),
    // one ds_write_b128 each, NO intermediate barriers
    {
        const int t = tid >> 8, kc = (tid >> 6) & 3, ln = tid & 63, m = ln & 31, h = ln >> 5;
        int kfo[8];
        #pragma unroll
        for (int j = 0; j < 8; ++j)
            kfo[j] = (8 * kc + 32 * (j >> 2) + 4 * h + (j & 3)) * 64 + 32 * t + m;
        #pragma unroll
        for (int node = 0; node < 12; ++node){
            const float* Wsrc = (node == 0) ? W1 : (Wg + (node - 1) * 4096);
            const float  scl  = NSCL[node];
            f16x8 v;
            #pragma unroll
            for (int j = 0; j < 8; ++j) v[j] = (f16)(scl * Wsrc[kfo[j]]);
            *(f16x8*)&wfrag[node][t][kc][ln][0] = v;
        }
    }
    __syncthreads();   // single barrier: all fragments complete

    #define WPTR(NI) (&wfrag[NI][0][0][lane][0])
    #define N1(NI, ACTI, A, OUT)        node32x2<ACTI,1>(WPTR(NI), &b_s[NI][0], hf4, A, A, A, OUT)
    #define N2(NI, ACTI, A, B, OUT)     node32x2<ACTI,2>(WPTR(NI), &b_s[NI][0], hf4, A, B, B, OUT)
    #define N3(NI, ACTI, A, B, C, OUT)  node32x2<ACTI,3>(WPTR(NI), &b_s[NI][0], hf4, A, B, C, OUT)

    const int wvid = tid >> 6;       // wave id 0..7

    // ================= MAIN LOOP: 2 tiles (64 pts) per wave per iter =================
    for (int it = 0; it < niter; ++it){
        const int tbase = ((it * gridDim.x + blockIdx.x) * 8 + wvid) * 2;
        if (tbase >= nt) break;

        f16x8 sg[2][4];
        int myp2[2];
        #pragma unroll
        for (int tt = 0; tt < 2; ++tt){
            const int myp = (tbase + tt) * 32 + n2;
            myp2[tt] = myp;
            const float xs = gx[myp], ys = gy[myp], zs = gz[myp], rs = gr[myp];
            const float xs2 = xs * xs;
            f16x8 nb;
            {
                const float4 a4 = *(const float4*)(gnoise + (size_t)myp * 16 + 8 * hf);
                const float4 b4 = *(const float4*)(gnoise + (size_t)myp * 16 + 8 * hf + 4);
                nb = cat8(pack4(a4.x, a4.y, a4.z, a4.w), pack4(b4.x, b4.y, b4.z, b4.w));
            }
            f16x4 pkg[2][4];
            #pragma unroll
            for (int t = 0; t < 2; ++t){
                f32x16 ac;
                #pragma unroll
                for (int i = 0; i < 16; ++i) ac[i] = 0.0f;
                ac = MFMA32(*(const f16x8*)&nfrag[t][lane][0], nb, ac);
                #pragma unroll
                for (int g = 0; g < 4; ++g){
                    const int fb = 32 * t + 8 * g + hf4;
                    const f32x4 wx2 = *(const f32x4*)&wvs[0][fb];   // C_GAU*Wx^2
                    const f32x4 wyt = *(const f32x4*)&wvs[1][fb];   // 2log2e*Wy
                    const f32x4 wz  = *(const f32x4*)&wvs[2][fb];
                    const f32x4 wr_ = *(const f32x4*)&wvs[3][fb];
                    const f32x4 bn  = *(const f32x4*)&bns[fb];      // 2log2e*b_noise
                    float gv[4];
                    #pragma unroll
                    for (int r = 0; r < 4; ++r){
                        float az = zs * wz[r];
                        float velu = az > 0.0f ? az : (fexp2(az * LOG2E) - 1.0f);
                        float vga = fexp2(xs2 * wx2[r]);
                        float vty = 1.0f - 2.0f * frcp(1.0f + fexp2(ys * wyt[r]));
                        float ar = rs * wr_[r];
                        float vsp = fmaxf(ar, 0.0f) + LN2 * flog2(1.0f + fexp2(-LOG2E * fabsf(ar)));
                        float vtp = 1.0f - 2.0f * frcp(1.0f + fexp2(ac[4 * g + r] + bn[r]));
                        gv[r] = fsin1((velu + vga + vty + vsp + vtp) * C_SIN);
                    }
                    pkg[t][g] = pack4(gv[0], gv[1], gv[2], gv[3]);
                }
            }
            #pragma unroll
            for (int kc = 0; kc < 4; ++kc) sg[tt][kc] = cat8(pkg[0][kc], pkg[1][kc]);
        }

        f16x8 h0[2][4], r0[2][4], r1[2][4], r2[2][4], r3[2][4];
        N1(0,  0, sg, h0);                 // h0 = tanh(g @ W1 + b1)
        N1(1,  0, h0, r0);                 // h1 = tanh(h0 W)
        N1(2,  1, r0, r1);                 // h2 = elu(h1 W)
        N2(3,  2, r1, h0, r2);             // h3 = softplus((h2+h0) W)
        N3(4,  3, r2, r0, h0, r3);         // h4 = sin((h3+h1+h0) W)
        N2(5,  4, r3, r1, r0);             // h5 = gauss((h4+h2) W)
        N2(6,  5, r0, r2, r1);             // h6 = sigmoid((h5+h3) W)
        N2(7,  0, r1, r3, r2);             // h7 = tanh((h6+h4) W)
        N3(8,  1, r2, r0, h0, r3);         // h8 = elu((h7+h5+h0) W)
        N2(9,  2, r3, r1, r0);             // h9 = softplus((h8+h6) W)
        N2(10, 3, r0, r2, r1);             // h10= sin((h9+h7) W)
        N2(11, 4, r1, r3, r2);             // h11= gauss((h10+h8) W)

        // ---- output: sigmoid folded into ofrag: out = rcp(1+exp2(om+bout)) ----
        #pragma unroll
        for (int tt = 0; tt < 2; ++tt){
            f32x16 om;
            #pragma unroll
            for (int i = 0; i < 16; ++i) om[i] = 0.0f;
            #pragma unroll
            for (int kc = 0; kc < 4; ++kc)
                om = MFMA32(*(const f16x8*)&ofrag[kc][lane][0], r2[tt][kc], om);
            if (hf == 0){
                #pragma unroll
                for (int r = 0; r < 3; ++r)
                    out[(size_t)myp2[tt] * 3 + r] = frcp(1.0f + fexp2(om[r] + bout_s[r]));
            }
        }
    }
    #undef N1
    #undef N2
    #undef N3
    #undef WPTR
}

extern "C" void kernel_launch(void* const* d_in, const int* in_sizes, int n_in,
                              void* d_out, int out_size, void* d_ws, size_t ws_size,
                              hipStream_t stream)
{
    const float* x       = (const float*)d_in[0];
    const float* y       = (const float*)d_in[1];
    const float* z       = (const float*)d_in[2];
    const float* r       = (const float*)d_in[3];
    const float* noise   = (const float*)d_in[4];
    const float* W_noise = (const float*)d_in[5];
    const float* b_noise = (const float*)d_in[6];
    const float* W_x     = (const float*)d_in[7];
    const float* W_y     = (const float*)d_in[8];
    const float* W_z     = (const float*)d_in[9];
    const float* W_r     = (const float*)d_in[10];
    const float* W1      = (const float*)d_in[11];
    const float* b1      = (const float*)d_in[12];
    const float* Wg      = (const float*)d_in[13];
    const float* bg      = (const float*)d_in[14];
    const float* W_out   = (const float*)d_in[15];
    const float* b_out   = (const float*)d_in[16];
    float* out = (float*)d_out;

    const int n     = in_sizes[0];
    const int nt    = n / 32;                       // 32-pt tiles (8192)
    const int grid  = 256;                          // 1 block per CU; prep once per CU
    const int tiles_per_pass = grid * 8 * 2;        // 8 waves x 2 tiles
    const int niter = (nt + tiles_per_pass - 1) / tiles_per_pass;
    inr_mfma8_kernel<<<dim3(grid), dim3(512), 0, stream>>>(
        x, y, z, r, noise, W_noise, b_noise, W_x, W_y, W_z, W_r,
        W1, b1, Wg, bg, W_out, b_out, out, nt, niter);
}